// Round 9
// baseline (237.362 us; speedup 1.0000x reference)
//
#include <hip/hip_runtime.h>
#include <stdint.h>

constexpr int SEQL = 512;
constexpr int DM = 256;
constexpr float SCQ = 0.50500066f;  // sqrt(1/sqrt(32) * log2(e))

typedef __attribute__((ext_vector_type(4))) float f32x4;
typedef __attribute__((ext_vector_type(8))) short short8;
typedef unsigned short u16;

// ---------------- helpers ----------------
__device__ __forceinline__ unsigned cvt_pk_bf16(float lo, float hi) {
  unsigned r;
  asm("v_cvt_pk_bf16_f32 %0, %1, %2" : "=v"(r) : "v"(lo), "v"(hi));
  return r;
}
__device__ __forceinline__ void gload_lds16(const void* g, void* l) {
  __builtin_amdgcn_global_load_lds(
      (const __attribute__((address_space(1))) void*)g,
      (__attribute__((address_space(3))) void*)l, 16, 0, 0);
}
__device__ __forceinline__ float wred_sum(float v) {
#pragma unroll
  for (int d = 32; d >= 1; d >>= 1) v += __shfl_xor(v, d, 64);
  return v;
}

// ---------------- weight pre-transpose: Wt[n][k] bf16 ----------------
struct W9 { const float* w[9]; };
__global__ __launch_bounds__(256) void wt_pre(W9 wlist, u16* out) {
  const float* W = wlist.w[blockIdx.y];
  const int n = threadIdx.x;
  const int k8 = blockIdx.x << 3;
  float v[8];
#pragma unroll
  for (int e = 0; e < 8; ++e) v[e] = W[(size_t)(k8 + e) * 256 + n];
  unsigned u4[4];
#pragma unroll
  for (int e2 = 0; e2 < 4; ++e2) u4[e2] = cvt_pk_bf16(v[2 * e2], v[2 * e2 + 1]);
  u16* dst = out + (size_t)blockIdx.y * 65536 + (size_t)n * 256 + k8;
  *(uint4*)dst = make_uint4(u4[0], u4[1], u4[2], u4[3]);
}

// ---------------- bf16 MFMA GEMM: C[8192,256] = A[8192,256]@W + bias, xscale ----------------
struct GemmSet { const void* A; const u16* Wt; const float* bias; void* C; float scale; };
struct GemmBatch { GemmSet s[4]; };

template <int ABF16, int OBF16>
__global__ __launch_bounds__(256, 2) void gemm_mfma(GemmBatch batch) {
  extern __shared__ char lds[];
  char* Al = lds;          // 32KB: A tile 64x256 bf16, XOR-swizzled
  char* Wl = lds + 32768;  // 32KB: Wt tile 64x256 bf16, XOR-swizzled
  const GemmSet S = batch.s[blockIdx.z];
  const int tid = threadIdx.x, lane = tid & 63, wave = tid >> 6;
  const int m0 = blockIdx.x << 6, n0 = blockIdx.y << 6;

#pragma unroll
  for (int it = 0; it < 8; ++it) {
    int chunk = (it << 8) + tid;
    int row = chunk >> 5, cc = chunk & 31;
    gload_lds16(S.Wt + (size_t)(n0 + row) * 256 + ((cc ^ (row & 7)) << 3),
                Wl + (it << 12) + (wave << 10));
  }
  if constexpr (ABF16) {
#pragma unroll
    for (int it = 0; it < 8; ++it) {
      int chunk = (it << 8) + tid;
      int row = chunk >> 5, cc = chunk & 31;
      gload_lds16((const u16*)S.A + (size_t)(m0 + row) * 256 + ((cc ^ (row & 7)) << 3),
                  Al + (it << 12) + (wave << 10));
    }
  } else {
#pragma unroll
    for (int it = 0; it < 16; ++it) {
      int idx = (it << 8) + tid;
      int row = idx >> 6, k4 = (idx & 63) << 2;
      float4 v = *(const float4*)((const float*)S.A + (size_t)(m0 + row) * 256 + k4);
      uint2 pk2;
      pk2.x = cvt_pk_bf16(v.x, v.y);
      pk2.y = cvt_pk_bf16(v.z, v.w);
      *(uint2*)(Al + (row << 9) + ((k4 << 1) ^ ((row & 7) << 4))) = pk2;
    }
  }
  __syncthreads();

  const int g = lane >> 4, cc = lane & 15;
  const int sw = cc & 7;
  f32x4 acc[4];
#pragma unroll
  for (int j = 0; j < 4; ++j) acc[j] = (f32x4){0.f, 0.f, 0.f, 0.f};
  const char* arow = Al + (size_t)((wave << 4) + cc) * 512;
  const char* wrow = Wl + (size_t)cc * 512;
#pragma unroll
  for (int kk = 0; kk < 8; ++kk) {
    const int so = (((kk << 2) + g) ^ sw) << 4;
    short8 ka = *(const short8*)(arow + so);
#pragma unroll
    for (int j = 0; j < 4; ++j) {
      short8 kb = *(const short8*)(wrow + (j << 13) + so);
      acc[j] = __builtin_amdgcn_mfma_f32_16x16x32_bf16(ka, kb, acc[j], 0, 0, 0);
    }
  }
#pragma unroll
  for (int j = 0; j < 4; ++j) {
    float bj = S.bias[n0 + (j << 4) + cc];
#pragma unroll
    for (int r = 0; r < 4; ++r) {
      float v = (acc[j][r] + bj) * S.scale;
      size_t off = (size_t)(m0 + (wave << 4) + (g << 2) + r) * 256 + n0 + (j << 4) + cc;
      if constexpr (OBF16)
        ((u16*)S.C)[off] = (u16)cvt_pk_bf16(v, v);
      else
        ((float*)S.C)[off] = v;
    }
  }
}

// ---------------- attention chain helpers (log2 domain, NO max-subtraction) ----------------
// m1 = m2 = 0 is numerically safe: scores pre-scaled by log2e/sqrt(32),
// exp2 args stay in [-10,10] with huge fp32 margin.
__device__ __forceinline__ float chain_sum(const float (&sq)[16], int tlq) {
  if (!__any(tlq >= 0)) return 0.f;
  float t = 0.f;
  if (__all(tlq >= 15)) {
#pragma unroll
    for (int T = 0; T < 16; ++T) t += __builtin_amdgcn_exp2f(sq[T]);
  } else {
#pragma unroll
    for (int T = 0; T < 16; ++T)
      t += (T <= tlq) ? __builtin_amdgcn_exp2f(sq[T]) : 0.f;
  }
  return t;
}
__device__ __forceinline__ void chain_decay(float (&sq)[16], int tlq, float djq, float seed,
                                            float S1, float ghs) {
  if (!__any(tlq >= 0)) return;  // fully masked: tot == 1 exactly
  float r = seed;
  if (__all(tlq >= 15)) {
#pragma unroll
    for (int T = 0; T < 16; ++T) {
      r += __builtin_amdgcn_exp2f(sq[T]);
      float u = fmaxf((S1 - r) * (djq - (float)T), 0.f);
      float tot = fmaxf(__builtin_amdgcn_exp2f(ghs * __builtin_amdgcn_sqrtf(u)), 1e-5f);
      sq[T] *= tot;  // ghs <= 0 so tot <= 1: upper clip never active
    }
  } else {
#pragma unroll
    for (int T = 0; T < 16; ++T) {
      float e = (T <= tlq) ? __builtin_amdgcn_exp2f(sq[T]) : 0.f;
      r += e;
      float u = fmaxf((S1 - r) * (djq - (float)T), 0.f);
      float tot = fmaxf(__builtin_amdgcn_exp2f(ghs * __builtin_amdgcn_sqrtf(u)), 1e-5f);
      sq[T] *= tot;
    }
  }
}
// r4-verified: pack ALL chains first, then PV (r5's interleaved variant failed).
__device__ __forceinline__ void chain_pack(const float (&sq)[16], float& S2,
                                           unsigned (&pkq)[8]) {
#pragma unroll
  for (int k = 0; k < 8; ++k) {
    float pa = __builtin_amdgcn_exp2f(sq[2 * k]);
    float pb = __builtin_amdgcn_exp2f(sq[2 * k + 1]);
    S2 += pa + pb;
    pkq[k] = cvt_pk_bf16(pa, pb);
  }
}
__device__ __forceinline__ void pv_q(const unsigned (&pkq)[8], int qidx, const char* vfb,
                                     f32x4& acc0, f32x4& acc1) {
#pragma unroll
  for (int hf = 0; hf < 2; ++hf) {
    union { unsigned u[4]; short8 s8; } ua;
    ua.u[0] = pkq[hf * 4 + 0]; ua.u[1] = pkq[hf * 4 + 1];
    ua.u[2] = pkq[hf * 4 + 2]; ua.u[3] = pkq[hf * 4 + 3];
    const int st = qidx * 2 + hf;
    short8 vb0 = *(const short8*)(vfb + (st << 11));
    short8 vb1 = *(const short8*)(vfb + (st << 11) + 1024);
    acc0 = __builtin_amdgcn_mfma_f32_16x16x32_bf16(ua.s8, vb0, acc0, 0, 0, 0);
    acc1 = __builtin_amdgcn_mfma_f32_16x16x32_bf16(ua.s8, vb1, acc1, 0, 0, 0);
  }
}

// ---------------- fused attention (bf16 in, bf16 out) ----------------
// BALANCED-J: j = 128q + 64p + 16g + T.
// K is NOT LDS-staged this round (r8 post-mortem: 76KB LDS -> 1 block/CU,
// OccupancyPercent ~20%, everything convoyed). K per (b,h) is 32KB ->
// L1-resident; QK^T A-fragments read directly from global: lane (g,c)
// tile T reads K[j, 8g..8g+8], j = 128(c&3) + 64p + 16((c>>2)&3) + T
// (same j<->score mapping as the old LDS permutation, re-derived).
// LDS = V 32KB + accR 8KB + red 2.5KB = 42.5KB -> 2-3 blocks/CU.
struct AttnSet {
  const u16* Q; const u16* K; const u16* V;
  const float* gam; u16* O;
  int qsb, qss, peek, zp;
};

// (512,2): live state ~90-100 VGPR; min-waves=4 forces the 64-VGPR bucket and
// spills ~420MB/dispatch (r4 post-mortem).
__global__ __launch_bounds__(512, 2) void attn_fused(AttnSet a0, AttnSet a1) {
  extern __shared__ char smem[];
  char* VfB = smem;                      // 32KB V B-fragments
  float* accR = (float*)(smem + 32768);  // 8KB pair-reduce
  float* red = (float*)(smem + 40960);   // 2.5KB: [4 chains][4 pr][2 p][16 c] + S2
  const int tid = threadIdx.x;
  const int lane = tid & 63, wave = tid >> 6;
  const int p = wave & 1, pr = wave >> 1;
  const AttnSet S = (blockIdx.x >> 7) ? a1 : a0;
  const int bh = blockIdx.x & 127;
  const int b = bh >> 3, h = bh & 7;
  const int y = blockIdx.y;
  const int g = lane >> 4, c = lane & 15;

  // ---- stage V scattered into PV B-fragment order
  const u16* Vb = S.V + ((size_t)b * SEQL) * DM + h * 32;
#pragma unroll
  for (int it = 0; it < 4; ++it) {
    int idx = (it << 9) + tid;
    int j = idx >> 2, dc = idx & 3, d0 = dc << 3;
    short8 v = *(const short8*)(Vb + (size_t)j * DM + d0);
    int q_ = j >> 7, p_ = (j >> 6) & 1, g_ = (j >> 4) & 3, tt = j & 15;
    int st_ = (q_ << 1) + (tt >> 3), e_ = tt & 7;
    char* base = VfB + (((p_ << 4) + (st_ << 1) + (d0 >> 4)) << 10) +
                 (((g_ << 4) + (d0 & 15)) << 4) + (e_ << 1);
    const unsigned* vu = (const unsigned*)&v;
#pragma unroll
    for (int e = 0; e < 4; ++e) {
      *(u16*)(base + (e << 5)) = (u16)(vu[e] & 0xffffu);
      *(u16*)(base + (e << 5) + 16) = (u16)(vu[e] >> 16);
    }
  }
  __syncthreads();

  const float gh2 = -log1pf(__expf(S.gam[h])) * 1.4426950408889634f;
  // K A-fragment base: j0 = 128(c&3) + 64p + 16((c>>2)&3); feature offset 8g.
  const u16* kptr = S.K + ((size_t)b * SEQL) * DM + h * 32 +
                    (size_t)(((c & 3) << 7) + (p << 6) + (((c >> 2) & 3) << 4)) * DM +
                    (g << 3);
  const char* vfb = VfB + (p << 14) + (lane << 4);
  const int rbase = (pr << 5) + c;
  const int jb0 = (p << 6) + (g << 4);

  for (int it = 0; it < 2; ++it) {
    const int sl = it ? (7 - y) : y;
    const int i0 = (sl << 6) + (pr << 4);
    const int i_row = i0 + c;
    short8 qf = *(const short8*)(S.Q + (size_t)b * S.qsb + (size_t)i_row * S.qss + h * 32 + (g << 3));

    // ---- QK^T (swapped): chain q holds j = 128q + 64p + 16g + T
    float s0a[16], s1a[16], s2a[16], s3a[16];
#pragma unroll
    for (int T = 0; T < 16; ++T) {
      short8 ka = *(const short8*)(kptr + (size_t)T * DM);  // global, L1-hot
      f32x4 d = __builtin_amdgcn_mfma_f32_16x16x32_bf16(
          ka, qf, (f32x4){0.f, 0.f, 0.f, 0.f}, 0, 0, 0);
      s0a[T] = d.x; s1a[T] = d.y; s2a[T] = d.z; s3a[T] = d.w;
    }
    const int ilim = i_row - 1 + S.peek;
    const int tl0 = ilim - jb0, tl1 = tl0 - 128, tl2 = tl0 - 256, tl3 = tl0 - 384;

    // ---- P2: masked-exp chain totals + within-chain g-scan
    float T0 = chain_sum(s0a, tl0), T1 = chain_sum(s1a, tl1);
    float T2 = chain_sum(s2a, tl2), T3 = chain_sum(s3a, tl3);
    float i0v = T0, i1v = T1, i2v = T2, i3v = T3, tU;
    tU = __shfl_up(i0v, 16, 64); i0v += (g >= 1) ? tU : 0.f;
    tU = __shfl_up(i0v, 32, 64); i0v += (g >= 2) ? tU : 0.f;
    tU = __shfl_up(i1v, 16, 64); i1v += (g >= 1) ? tU : 0.f;
    tU = __shfl_up(i1v, 32, 64); i1v += (g >= 2) ? tU : 0.f;
    tU = __shfl_up(i2v, 16, 64); i2v += (g >= 1) ? tU : 0.f;
    tU = __shfl_up(i2v, 32, 64); i2v += (g >= 2) ? tU : 0.f;
    tU = __shfl_up(i3v, 16, 64); i3v += (g >= 1) ? tU : 0.f;
    tU = __shfl_up(i3v, 32, 64); i3v += (g >= 2) ? tU : 0.f;
    float U0 = __shfl(i0v, c + 48, 64), U1 = __shfl(i1v, c + 48, 64);
    float U2 = __shfl(i2v, c + 48, 64), U3 = __shfl(i3v, c + 48, 64);
    float G0 = i0v - T0, G1 = i1v - T1, G2 = i2v - T2, G3 = i3v - T3;
    if (g == 0) {
      float* rT = red + rbase + (p << 4);
      rT[0] = U0; rT[128] = U1; rT[256] = U2; rT[384] = U3;
    }
    __syncthreads();  // B1
    const float* rO = red + rbase + ((1 - p) << 4);  // other wave's chain totals
    const float O0 = rO[0], O1 = rO[128], O2 = rO[256], O3 = rO[384];
    const float c1 = U0 + O0, c2 = c1 + U1 + O1, c3 = c2 + U2 + O2;
    const float S1 = c3 + U3 + O3;
    const float inv1 = (S1 > 0.f) ? (1.f / S1) : 0.f;
    const float ghs = gh2 * __builtin_amdgcn_sqrtf(inv1);
    // exclusive prefix in j-order (blocks ordered (q,p)): E_q = pre + p*O_q
    const float E0 = p ? O0 : 0.f;
    const float E1 = c1 + (p ? O1 : 0.f);
    const float E2 = c2 + (p ? O2 : 0.f);
    const float E3 = c3 + (p ? O3 : 0.f);

    // ---- P3: distance-decay (chain q window base = 128q + jb0)
    const float dj0 = (float)(i_row - jb0);
    chain_decay(s0a, tl0, dj0, E0 + G0, S1, ghs);
    chain_decay(s1a, tl1, dj0 - 128.f, E1 + G1, S1, ghs);
    chain_decay(s2a, tl2, dj0 - 256.f, E2 + G2, S1, ghs);
    chain_decay(s3a, tl3, dj0 - 384.f, E3 + G3, S1, ghs);

    // ---- P4: unmasked softmax numerators, pack p to bf16 (inv2 at epilogue)
    unsigned pk0[8], pk1[8], pk2[8], pk3[8];
    float S2 = 0.f;
    chain_pack(s0a, S2, pk0); chain_pack(s1a, S2, pk1);
    chain_pack(s2a, S2, pk2); chain_pack(s3a, S2, pk3);
    S2 += __shfl_xor(S2, 16, 64);
    S2 += __shfl_xor(S2, 32, 64);
    if (g == 0) red[512 + rbase + (p << 4)] = S2;

    // ---- P5: PV (overlaps the S2 LDS write)
    f32x4 acc0 = {0.f, 0.f, 0.f, 0.f}, acc1 = {0.f, 0.f, 0.f, 0.f};
    pv_q(pk0, 0, vfb, acc0, acc1);
    pv_q(pk1, 1, vfb, acc0, acc1);
    pv_q(pk2, 2, vfb, acc0, acc1);
    pv_q(pk3, 3, vfb, acc0, acc1);

    // ---- pair-reduce: p=1 publishes, single barrier, p=0 combines+stores
    if (p) {
      float* dst = accR + (pr << 9) + (lane << 3);
      *(f32x4*)dst = acc0;
      *(f32x4*)(dst + 4) = acc1;
    }
    __syncthreads();  // B2 (covers S2 slots AND accR)
    if (!p) {
      float inv2 = 1.f / (red[512 + rbase] + red[512 + rbase + 16]);
      if (S.zp && i_row == 0) inv2 = 0.f;
      const float* src = accR + (pr << 9) + (lane << 3);
      f32x4 o0 = *(const f32x4*)src;
      f32x4 o1 = *(const f32x4*)(src + 4);
      float iv[4];
#pragma unroll
      for (int r = 0; r < 4; ++r) iv[r] = __shfl(inv2, (g << 2) + r, 64);
      u16* orow = S.O + ((size_t)b * SEQL + i0 + (g << 2)) * DM + h * 32 + c;
#pragma unroll
      for (int r = 0; r < 4; ++r) {
        float v0 = (acc0[r] + o0[r]) * iv[r];
        float v1 = (acc1[r] + o1[r]) * iv[r];
        orow[(size_t)r * DM] = (u16)cvt_pk_bf16(v0, v0);
        orow[(size_t)r * DM + 16] = (u16)cvt_pk_bf16(v1, v1);
      }
    }
  }
}

// ---------------- add + LayerNorm (fp32 in, bf16 out), two sets ----------------
struct LnSet { const float* x; const float* res; int rstride; const float* g; const float* b; u16* out; };
__global__ __launch_bounds__(256, 4) void add_ln(LnSet sa, LnSet sb, int rows0) {
  const int row = (blockIdx.x << 2) + (threadIdx.x >> 6);
  const bool second = row >= rows0;
  const LnSet S = second ? sb : sa;
  const int r = second ? row - rows0 : row;
  const int lane = threadIdx.x & 63;
  float4 xv = *(const float4*)&S.x[(size_t)r * DM + (lane << 2)];
  float4 rv = *(const float4*)&S.res[(size_t)r * S.rstride + (lane << 2)];
  float4 v;
  v.x = xv.x + rv.x; v.y = xv.y + rv.y; v.z = xv.z + rv.z; v.w = xv.w + rv.w;
  float s = wred_sum(v.x + v.y + v.z + v.w);
  const float mean = s * (1.f / 256.f);
  float4 d;
  d.x = v.x - mean; d.y = v.y - mean; d.z = v.z - mean; d.w = v.w - mean;
  float q = wred_sum(d.x * d.x + d.y * d.y + d.z * d.z + d.w * d.w);
  const float rstd = rsqrtf(q * (1.f / 256.f) + 1e-5f);
  float4 gv = *(const float4*)&S.g[lane << 2];
  float4 bv = *(const float4*)&S.b[lane << 2];
  float ox = fmaf(gv.x * d.x, rstd, bv.x), oy = fmaf(gv.y * d.y, rstd, bv.y);
  float oz = fmaf(gv.z * d.z, rstd, bv.z), ow = fmaf(gv.w * d.w, rstd, bv.w);
  uint2 pk2;
  pk2.x = cvt_pk_bf16(ox, oy);
  pk2.y = cvt_pk_bf16(oz, ow);
  *(uint2*)&S.out[(size_t)r * DM + (lane << 2)] = pk2;
}

// ---------------- tiny precompute: q3 (bf16, 0.505-scaled), key3 ----------------
__global__ __launch_bounds__(256) void small_pre(
    const float* know, const float* qw, const float* qb,
    const float* lkw, const float* lkb, u16* q3, float* key3) {
  const int d = threadIdx.x;
  float acc = qb[d];
  for (int kk = 0; kk < 256; ++kk) acc = fmaf(know[kk], qw[kk * 256 + d], acc);
  acc *= SCQ;
  q3[d] = (u16)cvt_pk_bf16(acc, acc);
#pragma unroll
  for (int hh = 0; hh < 8; ++hh) {
    float a = lkb[d];
#pragma unroll
    for (int kk = 0; kk < 32; ++kk)
      a = fmaf(know[hh * 32 + kk], lkw[kk * 256 + d], a);
    key3[hh * 256 + d] = 1.f / (1.f + __expf(-a));
  }
}

// ---------------- final pooling (Hf bf16) ----------------
__global__ __launch_bounds__(256, 4) void final_combine(
    const float* qe, const u16* Hf, const float* key3,
    const float* lvw, const float* lvb, float* out) {
  __shared__ float hl[256];
  __shared__ float red[4][8];
  const int n = blockIdx.x, d = threadIdx.x;
  const int lane = d & 63, wv = d >> 6;
  hl[d] = __uint_as_float(((unsigned)Hf[(size_t)n * DM + d]) << 16);
  const float qd = qe[(size_t)n * DM + d];
  float part[8];
#pragma unroll
  for (int hh = 0; hh < 8; ++hh) part[hh] = wred_sum(key3[hh * 256 + d] * qd);
  if (lane == 0) {
#pragma unroll
    for (int hh = 0; hh < 8; ++hh) red[wv][hh] = part[hh];
  }
  __syncthreads();
  float beta[8];
#pragma unroll
  for (int hh = 0; hh < 8; ++hh)
    beta[hh] = red[0][hh] + red[1][hh] + red[2][hh] + red[3][hh];
  float mb = beta[0];
#pragma unroll
  for (int hh = 1; hh < 8; ++hh) mb = fmaxf(mb, beta[hh]);
  float al[8], se = 0.f;
#pragma unroll
  for (int hh = 0; hh < 8; ++hh) { al[hh] = __expf(beta[hh] - mb); se += al[hh]; }
  const float inva = 1.f / se;
  float acc[8];
#pragma unroll
  for (int hh = 0; hh < 8; ++hh) acc[hh] = 0.f;
#pragma unroll
  for (int kk = 0; kk < 32; ++kk) {
    float w = lvw[kk * 256 + d];
#pragma unroll
    for (int hh = 0; hh < 8; ++hh) acc[hh] = fmaf(hl[hh * 32 + kk], w, acc[hh]);
  }
  const float bd = lvb[d];
  float o = 0.f;
#pragma unroll
  for (int hh = 0; hh < 8; ++hh) {
    float vv = 1.f / (1.f + __expf(-(acc[hh] + bd)));
    o = fmaf(al[hh] * inva, vv, o);
  }
  out[(size_t)n * DM + d] = o;
}

// ---------------- host launch ----------------
extern "C" void kernel_launch(void* const* d_in, const int* in_sizes, int n_in,
                              void* d_out, int out_size, void* d_ws, size_t ws_size,
                              hipStream_t stream) {
  (void)in_sizes; (void)n_in; (void)out_size; (void)ws_size;
  const float* q_emb  = (const float*)d_in[0];
  const float* qa_emb = (const float*)d_in[1];
  const float* b1_qw = (const float*)d_in[2];   const float* b1_qb = (const float*)d_in[3];
  const float* b1_vw = (const float*)d_in[4];   const float* b1_vb = (const float*)d_in[5];
  const float* b1_ow = (const float*)d_in[6];   const float* b1_ob = (const float*)d_in[7];
  const float* b1_gam = (const float*)d_in[8];
  const float* b1_lng = (const float*)d_in[9];  const float* b1_lnb = (const float*)d_in[10];
  const float* b2_qw = (const float*)d_in[11];  const float* b2_qb = (const float*)d_in[12];
  const float* b2_vw = (const float*)d_in[13];  const float* b2_vb = (const float*)d_in[14];
  const float* b2_ow = (const float*)d_in[15];  const float* b2_ob = (const float*)d_in[16];
  const float* b2_gam = (const float*)d_in[17];
  const float* b2_lng = (const float*)d_in[18]; const float* b2_lnb = (const float*)d_in[19];
  const float* b3_qw = (const float*)d_in[20];  const float* b3_qb = (const float*)d_in[21];
  const float* b3_kw = (const float*)d_in[22];  const float* b3_kb = (const float*)d_in[23];
  const float* b3_vw = (const float*)d_in[24];  const float* b3_vb = (const float*)d_in[25];
  const float* b3_ow = (const float*)d_in[26];  const float* b3_ob = (const float*)d_in[27];
  const float* b3_gam = (const float*)d_in[28];
  const float* b3_lng = (const float*)d_in[29]; const float* b3_lnb = (const float*)d_in[30];
  const float* know = (const float*)d_in[31];
  const float* lk_w = (const float*)d_in[32];   const float* lk_b = (const float*)d_in[33];
  const float* lv_w = (const float*)d_in[34];   const float* lv_b = (const float*)d_in[35];

  // workspace layout
  u16* wtb = (u16*)d_ws;                                   // 9*65536*2 = 1179648 B
  u16* q3 = (u16*)((char*)d_ws + 1179648);                 // 512 B
  float* key3 = (float*)((char*)d_ws + 1180160);           // 8192 B
  char* pool = (char*)d_ws + 1188352;
  const size_t SLOT = 2097152;  // elements per buffer (8192*256)
  u16* s0 = (u16*)pool;
  u16* s1 = s0 + SLOT; u16* s2 = s1 + SLOT; u16* s3 = s2 + SLOT;
  u16* s4 = s3 + SLOT; u16* s5 = s4 + SLOT; u16* s6 = s5 + SLOT;
  float* f0 = (float*)(pool + 7 * SLOT * 2);
  float* f1 = f0 + SLOT;

  const int SMB = 43520;  // 32K Vfrag + 8K accR + 2.5K red (K read from L1/L2)
  (void)hipFuncSetAttribute((const void*)attn_fused,
                            hipFuncAttributeMaxDynamicSharedMemorySize, SMB);
  (void)hipFuncSetAttribute((const void*)&gemm_mfma<0, 1>,
                            hipFuncAttributeMaxDynamicSharedMemorySize, 65536);
  (void)hipFuncSetAttribute((const void*)&gemm_mfma<1, 0>,
                            hipFuncAttributeMaxDynamicSharedMemorySize, 65536);
  (void)hipFuncSetAttribute((const void*)&gemm_mfma<1, 1>,
                            hipFuncAttributeMaxDynamicSharedMemorySize, 65536);

  // weight transpose + tiny precompute
  W9 w9{{b1_qw, b1_vw, b1_ow, b2_qw, b2_vw, b2_ow, b3_kw, b3_vw, b3_ow}};
  wt_pre<<<dim3(32, 9), 256, 0, stream>>>(w9, wtb);
  small_pre<<<1, 256, 0, stream>>>(know, b3_qw, b3_qb, lk_w, lk_b, q3, key3);

  // q/v projections for blocks 1&2 (q-buffers pre-scaled by sqrt(SC2))
  GemmBatch g1;
  g1.s[0] = {q_emb,  wtb + 0 * 65536, b1_qb, s0, SCQ};
  g1.s[1] = {q_emb,  wtb + 1 * 65536, b1_vb, s1, 1.f};
  g1.s[2] = {qa_emb, wtb + 3 * 65536, b2_qb, s2, SCQ};
  g1.s[3] = {qa_emb, wtb + 4 * 65536, b2_vb, s3, 1.f};
  gemm_mfma<0, 1><<<dim3(128, 4, 4), 256, 65536, stream>>>(g1);

  // merged attention blocks 1&2
  AttnSet A1{s0, s0, s1, b1_gam, s4, SEQL * DM, DM, 1, 0};
  AttnSet A2{s2, s2, s3, b2_gam, s5, SEQL * DM, DM, 1, 0};
  attn_fused<<<dim3(256, 4), 512, SMB, stream>>>(A1, A2);

  // out-projections
  GemmBatch g2;
  g2.s[0] = {s4, wtb + 2 * 65536, b1_ob, f0, 1.f};
  g2.s[1] = {s5, wtb + 5 * 65536, b2_ob, f1, 1.f};
  g2.s[2] = g2.s[0]; g2.s[3] = g2.s[0];
  gemm_mfma<1, 0><<<dim3(128, 4, 2), 256, 65536, stream>>>(g2);

  // add+LN blocks 1&2 -> HQ (s1), HA (s3)
  LnSet L1{f0, q_emb, DM, b1_lng, b1_lnb, s1};
  LnSet L2{f1, qa_emb, DM, b2_lng, b2_lnb, s3};
  add_ln<<<4096, 256, 0, stream>>>(L1, L2, 8192);

  // block3 k/v projections -> Kb3 (s4, 0.505-scaled), Vb3 (s5)
  GemmBatch g3;
  g3.s[0] = {s1, wtb + 6 * 65536, b3_kb, s4, SCQ};
  g3.s[1] = {s3, wtb + 7 * 65536, b3_vb, s5, 1.f};
  g3.s[2] = g3.s[0]; g3.s[3] = g3.s[0];
  gemm_mfma<1, 1><<<dim3(128, 4, 2), 256, 65536, stream>>>(g3);

  // block3 attention (broadcast q3, strict mask, zero_pad)
  AttnSet A3{q3, s4, s5, b3_gam, s0, 0, 0, 0, 1};
  attn_fused<<<dim3(128, 4), 512, SMB, stream>>>(A3, A3);

  // block3 out-projection + add+LN -> Hf (s6)
  GemmBatch g4;
  g4.s[0] = {s0, wtb + 8 * 65536, b3_ob, f0, 1.f};
  g4.s[1] = g4.s[0]; g4.s[2] = g4.s[0]; g4.s[3] = g4.s[0];
  gemm_mfma<1, 0><<<dim3(128, 4, 1), 256, 65536, stream>>>(g4);
  LnSet L3{f0, know, 0, b3_lng, b3_lnb, s6};
  add_ln<<<2048, 256, 0, stream>>>(L3, L3, 8192);

  // final pooling
  final_combine<<<8192, 256, 0, stream>>>(q_emb, s6, key3, lv_w, lv_b, (float*)d_out);
}